// Round 2
// baseline (440.123 us; speedup 1.0000x reference)
//
#include <hip/hip_runtime.h>
#include <hip/hip_bf16.h>

// FastFood layer: out[m, r*1024+j] = S[r,j]/32 * FWHT( G[r,:] * FWHT(x[m,:]*B[r,:])[P[r,:]] )[j]
// Output is FLOAT32 (reference computes in fp32 throughout).
// One wave = 2 rows. Per row-half (32 lanes): 1024 elems = 32 regs/lane.
// FWHT_1024 = regFWHT32 (5 bits) + LDS transpose + regFWHT32 (5 bits).
// LDS mapping phys = idx + (idx>>5): conflict-free for all structured phases,
// additive so offsets fold into ds immediate fields.

__device__ __forceinline__ void fwht32(float (&v)[32]) {
#pragma unroll
    for (int h = 1; h < 32; h <<= 1) {
#pragma unroll
        for (int i = 0; i < 32; ++i) {
            if ((i & h) == 0) {
                float a = v[i];
                float b = v[i | h];
                v[i]     = a + b;
                v[i | h] = a - b;
            }
        }
    }
}

__global__ __launch_bounds__(256, 4) void fastfood_kernel(
    const float* __restrict__ x,
    const float* __restrict__ Bm,
    const float* __restrict__ Gm,
    const float* __restrict__ Sm,
    const int*   __restrict__ Pm,
    float* __restrict__ out)
{
    // 4 waves/block, 2112 padded words per wave (2 rows x 1056)
    __shared__ float lds[4 * 2112];

    const int tid  = threadIdx.x;
    const int wv   = tid >> 6;
    const int lane = tid & 63;
    const int l5   = lane >> 5;   // row select within wave
    const int lh   = lane & 31;   // 5-bit lane id within row-half
    const int rp   = blockIdx.x * 4 + wv;   // row pair index
    const int row  = rp * 2 + l5;

    float* __restrict__ W = &lds[wv * 2112 + l5 * 1056];

    // ---- load x row, layout alpha: reg k=(q,t) <-> j = q*128 + lh*4 + t ----
    float xs[32];
    {
        const float4* x4 = reinterpret_cast<const float4*>(x) + (size_t)row * 256;
#pragma unroll
        for (int q = 0; q < 8; ++q) {
            float4 f = x4[q * 32 + lh];
            xs[4*q+0] = f.x * 0.03125f;   // fold 1/sqrt(1024) here (everything is linear)
            xs[4*q+1] = f.y * 0.03125f;
            xs[4*q+2] = f.z * 0.03125f;
            xs[4*q+3] = f.w * 0.03125f;
        }
    }

    // per-phase LDS lane bases (word units), phys = idx + (idx>>5)
    const int baseA = lh * 4 + (lh >> 3);                // alpha: + q*132 + t
    const int baseB = (lh >> 2) * 132 + (lh & 3);        // beta:  + m*4 + (m>>3)
    const int baseG = lh * 33;                           // gamma: + m
    const int baseE = lh;                                // eps:   + m*33

#pragma unroll 1
    for (int r = 0; r < 4; ++r) {
        float v[32];

        // v = (x/32) * B[r]   (alpha layout, float4 loads)
        {
            const float4* B4 = reinterpret_cast<const float4*>(Bm) + r * 256;
#pragma unroll
            for (int q = 0; q < 8; ++q) {
                float4 b = B4[q * 32 + lh];
                v[4*q+0] = xs[4*q+0] * b.x;
                v[4*q+1] = xs[4*q+1] * b.y;
                v[4*q+2] = xs[4*q+2] * b.z;
                v[4*q+3] = xs[4*q+3] * b.w;
            }
        }

        fwht32(v);                        // FWHT over j bits {0,1,7,8,9}

        // transpose alpha -> beta through LDS
#pragma unroll
        for (int k = 0; k < 32; ++k)
            W[baseA + (k >> 2) * 132 + (k & 3)] = v[k];
        __syncthreads();
#pragma unroll
        for (int m = 0; m < 32; ++m)
            v[m] = W[baseB + m * 4 + (m >> 3)];

        fwht32(v);                        // FWHT over j bits {2..6}  -> h1 complete (beta)

        // publish h1, then permutation-gather into gamma (lane owns j = lh*32 + m)
#pragma unroll
        for (int m = 0; m < 32; ++m)
            W[baseB + m * 4 + (m >> 3)] = v[m];
        __syncthreads();
        {
            const int4*   P4 = reinterpret_cast<const int4*>(Pm) + r * 256;
            const float4* G4 = reinterpret_cast<const float4*>(Gm) + r * 256;
#pragma unroll
            for (int g = 0; g < 8; ++g) {
                int4   p  = P4[lh * 8 + g];
                float4 gg = G4[lh * 8 + g];
                v[4*g+0] = W[p.x + (p.x >> 5)] * gg.x;
                v[4*g+1] = W[p.y + (p.y >> 5)] * gg.y;
                v[4*g+2] = W[p.z + (p.z >> 5)] * gg.z;
                v[4*g+3] = W[p.w + (p.w >> 5)] * gg.w;
            }
        }

        fwht32(v);                        // FWHT over j bits {0..4}

        // transpose gamma -> epsilon through LDS
#pragma unroll
        for (int m = 0; m < 32; ++m)
            W[baseG + m] = v[m];
        __syncthreads();
#pragma unroll
        for (int m = 0; m < 32; ++m)
            v[m] = W[baseE + m * 33];

        fwht32(v);                        // FWHT over j bits {5..9} -> h2 complete (epsilon)

        // scale by S and store fp32; epsilon layout: j = m*32 + lh (contiguous across lanes)
        {
            const float* Sr = Sm + r * 1024;
            float* op = out + (size_t)row * 4096 + r * 1024;
#pragma unroll
            for (int m = 0; m < 32; ++m) {
                float s = Sr[m * 32 + lh];
                op[m * 32 + lh] = v[m] * s;
            }
        }
        __syncthreads();  // protect next iteration's transpose writes vs this one's reads
    }
}

extern "C" void kernel_launch(void* const* d_in, const int* in_sizes, int n_in,
                              void* d_out, int out_size, void* d_ws, size_t ws_size,
                              hipStream_t stream) {
    const float* x = (const float*)d_in[0];
    const float* B = (const float*)d_in[1];
    const float* G = (const float*)d_in[2];
    const float* S = (const float*)d_in[3];
    const int*   P = (const int*)d_in[4];
    float* out = (float*)d_out;

    const int M = in_sizes[0] / 1024;        // 16384 rows
    const int blocks = M / 8;                // 8 rows per block (4 waves x 2 rows)

    hipLaunchKernelGGL(fastfood_kernel, dim3(blocks), dim3(256), 0, stream,
                       x, B, G, S, P, out);
}

// Round 3
// 393.477 us; speedup vs baseline: 1.1185x; 1.1185x over previous
//
#include <hip/hip_runtime.h>
#include <hip/hip_bf16.h>

// FastFood layer: out[m, r*1024+j] = S[r,j]/32 * FWHT( G[r,:] * FWHT(x[m,:]*B[r,:])[P[r,:]] )[j]
// Output is FLOAT32 (reference computes in fp32 throughout).
// One wave = 2 rows. Per row-half (32 lanes): 1024 elems = 32 regs/lane.
// FWHT_1024 = regFWHT32 (5 bits) + LDS transpose + regFWHT32 (5 bits).
// LDS mapping phys = idx + (idx>>5): conflict-free for all structured phases,
// additive so offsets fold into ds immediate fields.
//
// R2 note: __launch_bounds__(256,4) forced VGPR_Count=64 -> v[32]+xs[32] spilled
// to scratch (FETCH 236MB vs 70MB ideal, WRITE 365MB vs 268MB). LDS already caps
// occupancy at 4 blocks/CU (== 128-VGPR budget), so relax the cap: (256,2).

__device__ __forceinline__ void fwht32(float (&v)[32]) {
#pragma unroll
    for (int h = 1; h < 32; h <<= 1) {
#pragma unroll
        for (int i = 0; i < 32; ++i) {
            if ((i & h) == 0) {
                float a = v[i];
                float b = v[i | h];
                v[i]     = a + b;
                v[i | h] = a - b;
            }
        }
    }
}

__global__ __launch_bounds__(256, 2) void fastfood_kernel(
    const float* __restrict__ x,
    const float* __restrict__ Bm,
    const float* __restrict__ Gm,
    const float* __restrict__ Sm,
    const int*   __restrict__ Pm,
    float* __restrict__ out)
{
    // 4 waves/block, 2112 padded words per wave (2 rows x 1056)
    __shared__ float lds[4 * 2112];

    const int tid  = threadIdx.x;
    const int wv   = tid >> 6;
    const int lane = tid & 63;
    const int l5   = lane >> 5;   // row select within wave
    const int lh   = lane & 31;   // 5-bit lane id within row-half
    const int rp   = blockIdx.x * 4 + wv;   // row pair index
    const int row  = rp * 2 + l5;

    float* __restrict__ W = &lds[wv * 2112 + l5 * 1056];

    // ---- load x row, layout alpha: reg k=(q,t) <-> j = q*128 + lh*4 + t ----
    float xs[32];
    {
        const float4* x4 = reinterpret_cast<const float4*>(x) + (size_t)row * 256;
#pragma unroll
        for (int q = 0; q < 8; ++q) {
            float4 f = x4[q * 32 + lh];
            xs[4*q+0] = f.x * 0.03125f;   // fold 1/sqrt(1024) here (everything is linear)
            xs[4*q+1] = f.y * 0.03125f;
            xs[4*q+2] = f.z * 0.03125f;
            xs[4*q+3] = f.w * 0.03125f;
        }
    }

    // per-phase LDS lane bases (word units), phys = idx + (idx>>5)
    const int baseA = lh * 4 + (lh >> 3);                // alpha: + q*132 + t
    const int baseB = (lh >> 2) * 132 + (lh & 3);        // beta:  + m*4 + (m>>3)
    const int baseG = lh * 33;                           // gamma: + m
    const int baseE = lh;                                // eps:   + m*33

#pragma unroll 1
    for (int r = 0; r < 4; ++r) {
        float v[32];

        // v = (x/32) * B[r]   (alpha layout, float4 loads)
        {
            const float4* B4 = reinterpret_cast<const float4*>(Bm) + r * 256;
#pragma unroll
            for (int q = 0; q < 8; ++q) {
                float4 b = B4[q * 32 + lh];
                v[4*q+0] = xs[4*q+0] * b.x;
                v[4*q+1] = xs[4*q+1] * b.y;
                v[4*q+2] = xs[4*q+2] * b.z;
                v[4*q+3] = xs[4*q+3] * b.w;
            }
        }

        fwht32(v);                        // FWHT over j bits {0,1,7,8,9}

        // transpose alpha -> beta through LDS
#pragma unroll
        for (int k = 0; k < 32; ++k)
            W[baseA + (k >> 2) * 132 + (k & 3)] = v[k];
        __syncthreads();
#pragma unroll
        for (int m = 0; m < 32; ++m)
            v[m] = W[baseB + m * 4 + (m >> 3)];

        fwht32(v);                        // FWHT over j bits {2..6}  -> h1 complete (beta)

        // publish h1, then permutation-gather into gamma (lane owns j = lh*32 + m)
#pragma unroll
        for (int m = 0; m < 32; ++m)
            W[baseB + m * 4 + (m >> 3)] = v[m];
        __syncthreads();
        {
            const int4*   P4 = reinterpret_cast<const int4*>(Pm) + r * 256;
            const float4* G4 = reinterpret_cast<const float4*>(Gm) + r * 256;
#pragma unroll
            for (int g = 0; g < 8; ++g) {
                int4   p  = P4[lh * 8 + g];
                float4 gg = G4[lh * 8 + g];
                v[4*g+0] = W[p.x + (p.x >> 5)] * gg.x;
                v[4*g+1] = W[p.y + (p.y >> 5)] * gg.y;
                v[4*g+2] = W[p.z + (p.z >> 5)] * gg.z;
                v[4*g+3] = W[p.w + (p.w >> 5)] * gg.w;
            }
        }

        fwht32(v);                        // FWHT over j bits {0..4}

        // transpose gamma -> epsilon through LDS
#pragma unroll
        for (int m = 0; m < 32; ++m)
            W[baseG + m] = v[m];
        __syncthreads();
#pragma unroll
        for (int m = 0; m < 32; ++m)
            v[m] = W[baseE + m * 33];

        fwht32(v);                        // FWHT over j bits {5..9} -> h2 complete (epsilon)

        // scale by S and store fp32; epsilon layout: j = m*32 + lh (contiguous across lanes)
        {
            const float* Sr = Sm + r * 1024;
            float* op = out + (size_t)row * 4096 + r * 1024;
#pragma unroll
            for (int m = 0; m < 32; ++m) {
                float s = Sr[m * 32 + lh];
                op[m * 32 + lh] = v[m] * s;
            }
        }
        __syncthreads();  // protect next iteration's transpose writes vs this one's reads
    }
}

extern "C" void kernel_launch(void* const* d_in, const int* in_sizes, int n_in,
                              void* d_out, int out_size, void* d_ws, size_t ws_size,
                              hipStream_t stream) {
    const float* x = (const float*)d_in[0];
    const float* B = (const float*)d_in[1];
    const float* G = (const float*)d_in[2];
    const float* S = (const float*)d_in[3];
    const int*   P = (const int*)d_in[4];
    float* out = (float*)d_out;

    const int M = in_sizes[0] / 1024;        // 16384 rows
    const int blocks = M / 8;                // 8 rows per block (4 waves x 2 rows)

    hipLaunchKernelGGL(fastfood_kernel, dim3(blocks), dim3(256), 0, stream,
                       x, B, G, S, P, out);
}